// Round 6
// baseline (258.301 us; speedup 1.0000x reference)
//
#include <hip/hip_runtime.h>
#include <cstdint>
#include <cstddef>

#define NB 8
#define NS 4096
#define NN 2048
#define NH 768
#define NK 50
#define SEG 256
#define NSEG (NS / SEG)    // 16

// ---------------------------------------------------------------------------
// K1a: sequential f32 chain per (b,h) column; stores only 256-row-boundary
// checkpoints. Wave 0 = consumer: 4-slot x 16-row LDS ring fed by
// global_load_lds, drained with counted vmcnt (unchanged from passing R5 —
// bit-exact np.cumsum order). Waves 1-3 = prefetchers: stream the same rows
// (striped r % 3) into a dummy LDS scratch to warm L2 ahead of the consumer.
// No cross-wave sync — prefetch is a pure hint; races only touch scratch.
// ---------------------------------------------------------------------------
__global__ __launch_bounds__(256) void k1a_chk(const float* __restrict__ x,
                                               float* __restrict__ chk) {
  const int w    = blockIdx.x;              // 0..95 = 8 b x 12 h-slices
  const int b    = w / 12;
  const int h0   = (w % 12) * 64;
  const int wave = threadIdx.x >> 6;
  const int lane = threadIdx.x & 63;
  const int h    = h0 + lane;

  const float* gx = x + (size_t)b * NS * NH + h0 + lane;  // per-lane column

  __shared__ float ring[4 * 16 * 64];       // 4 slots x 16 rows x 256B = 16 KB
  __shared__ float scratch[64];             // prefetch sink (contents unused)

  if (wave == 0) {
    // -------- consumer: EXACTLY the R5 structure (bit-exact chain) --------
    auto issue = [&](int g) {
      const float* src = gx + (size_t)g * 16 * NH;
      float*       dst = &ring[(g & 3) * (16 * 64)];
#pragma unroll
      for (int r = 0; r < 16; ++r)
        __builtin_amdgcn_global_load_lds(
            (const __attribute__((address_space(1))) uint32_t*)(src + (size_t)r * NH),
            (__attribute__((address_space(3))) uint32_t*)(dst + r * 64),
            4, 0, 0);
    };

    float acc = 0.0f;
    auto consume = [&](int g) {
      const float* s = &ring[(g & 3) * (16 * 64)];
#pragma unroll
      for (int r = 0; r < 16; ++r) acc += s[r * 64 + lane];
      if ((g & 15) == 15 && g != 255)
        chk[((size_t)b * NSEG + (size_t)(g + 1) / 16) * NH + h] = acc;
    };

    issue(0); issue(1); issue(2);           // prologue: 48 loads in flight

    for (int g = 0; g <= 252; ++g) {
      asm volatile("s_waitcnt vmcnt(32)" ::: "memory");   // group g landed
      __builtin_amdgcn_sched_barrier(0);
      consume(g);
      issue(g + 3);
    }
    asm volatile("s_waitcnt vmcnt(32)" ::: "memory");
    __builtin_amdgcn_sched_barrier(0);
    consume(253);
    asm volatile("s_waitcnt vmcnt(16)" ::: "memory");
    __builtin_amdgcn_sched_barrier(0);
    consume(254);
    asm volatile("s_waitcnt vmcnt(0)" ::: "memory");
    __builtin_amdgcn_sched_barrier(0);
    consume(255);
  } else {
    // -------- prefetchers: warm L2 with rows r == (wave-1) mod 3 ----------
    const int p = wave - 1;                 // 0,1,2
    for (int t = p; t < NS; t += 48) {      // 16 rows per iter, stride 3
#pragma unroll
      for (int j = 0; j < 16; ++j) {
        int r = t + 3 * j;
        if (r < NS)
          __builtin_amdgcn_global_load_lds(
              (const __attribute__((address_space(1))) uint32_t*)(gx + (size_t)r * NH),
              (__attribute__((address_space(3))) uint32_t*)(&scratch[0]),
              4, 0, 0);
      }
      asm volatile("s_waitcnt vmcnt(32)" ::: "memory");   // pace: ~32-48 deep
    }
    asm volatile("s_waitcnt vmcnt(0)" ::: "memory");
  }
}

// ---------------------------------------------------------------------------
// K1b: fill P. 1536 waves; each replays one 256-row segment from its exact
// checkpoint accumulator -> identical f32 add sequence -> bit-exact cumsum.
// [UNCHANGED]
// ---------------------------------------------------------------------------
__global__ __launch_bounds__(256) void k1b_fill(const float* __restrict__ x,
                                                const float* __restrict__ chk,
                                                float* __restrict__ P) {
  const int gw   = blockIdx.x * 4 + (threadIdx.x >> 6);   // 0..1535
  const int lane = threadIdx.x & 63;
  const int b    = gw / (12 * NSEG);
  const int rem  = gw % (12 * NSEG);
  const int slice = rem / NSEG, seg = rem % NSEG;
  const int h = slice * 64 + lane;

  const float* gx = x + ((size_t)b * NS + (size_t)seg * SEG) * NH + h;
  float*       gp = P + ((size_t)b * (NS + 1) + (size_t)seg * SEG + 1) * NH + h;

  if (seg == 0) P[(size_t)b * (NS + 1) * NH + h] = 0.0f;  // P[b,0,h] = 0
  float acc = (seg == 0) ? 0.0f : chk[((size_t)b * NSEG + seg) * NH + h];

  float va[32], vb[32];
#pragma unroll
  for (int j = 0; j < 32; ++j) va[j] = gx[(size_t)j * NH];

  for (int c = 0; c < 8; c += 2) {
    {   // load chunk c+1
      const float* s = gx + (size_t)(c + 1) * 32 * NH;
#pragma unroll
      for (int j = 0; j < 32; ++j) vb[j] = s[(size_t)j * NH];
    }
    {   // consume chunk c
      float* op = gp + (size_t)c * 32 * NH;
#pragma unroll
      for (int j = 0; j < 32; ++j) { acc += va[j]; op[(size_t)j * NH] = acc; }
    }
    if (c + 2 < 8) {
      const float* s = gx + (size_t)(c + 2) * 32 * NH;
#pragma unroll
      for (int j = 0; j < 32; ++j) va[j] = s[(size_t)j * NH];
    }
    {   // consume chunk c+1
      float* op = gp + (size_t)(c + 1) * 32 * NH;
#pragma unroll
      for (int j = 0; j < 32; ++j) { acc += vb[j]; op[(size_t)j * NH] = acc; }
    }
  }
}

// ---------------------------------------------------------------------------
// K2: span scores. [UNCHANGED from passing version]
// ---------------------------------------------------------------------------
__global__ __launch_bounds__(256) void k2_scores(const float* __restrict__ P,
                                                 const int* __restrict__ starts,
                                                 const int* __restrict__ lens,
                                                 const float* __restrict__ anchor,
                                                 float* __restrict__ scores) {
  const int lane  = threadIdx.x & 63;
  const int gwave = blockIdx.x * 4 + (threadIdx.x >> 6);
  const int nwv   = gridDim.x * 4;

  float4 a[3][3];
#pragma unroll
  for (int c = 0; c < 3; ++c)
#pragma unroll
    for (int p = 0; p < 3; ++p)
      a[c][p] = *reinterpret_cast<const float4*>(anchor + c * NH + lane * 4 + p * 256);

  for (int sp = gwave; sp < NB * NN; sp += nwv) {
    const int b  = sp >> 11;
    const int st = starts[sp];
    const int nt = lens[sp] + 1;
    const int en = st + nt;
    const float fnt = (float)nt;
    const float* ps = P + ((size_t)b * (NS + 1) + st) * NH + lane * 4;
    const float* pe = P + ((size_t)b * (NS + 1) + en) * NH + lane * 4;
    float d0 = 0.f, d1 = 0.f, d2 = 0.f;
#pragma unroll
    for (int p = 0; p < 3; ++p) {
      float4 vs = *reinterpret_cast<const float4*>(ps + p * 256);
      float4 ve = *reinterpret_cast<const float4*>(pe + p * 256);
      float ex = (ve.x - vs.x) / fnt;
      float ey = (ve.y - vs.y) / fnt;
      float ez = (ve.z - vs.z) / fnt;
      float ew = (ve.w - vs.w) / fnt;
      d0 += ex * a[0][p].x + ey * a[0][p].y + ez * a[0][p].z + ew * a[0][p].w;
      d1 += ex * a[1][p].x + ey * a[1][p].y + ez * a[1][p].z + ew * a[1][p].w;
      d2 += ex * a[2][p].x + ey * a[2][p].y + ez * a[2][p].z + ew * a[2][p].w;
    }
#pragma unroll
    for (int o = 32; o > 0; o >>= 1) {
      d0 += __shfl_xor(d0, o);
      d1 += __shfl_xor(d1, o);
      d2 += __shfl_xor(d2, o);
    }
    if (lane == 0) scores[sp] = fmaxf(d0, fmaxf(d1, d2));
  }
}

// ---------------------------------------------------------------------------
// K3: top-50 per batch. [UNCHANGED]
// ---------------------------------------------------------------------------
__global__ __launch_bounds__(256) void k3_topk(const float* __restrict__ scores,
                                               int* __restrict__ topidx) {
  const int b   = blockIdx.x;
  const int tid = threadIdx.x;
  __shared__ unsigned long long key[NN];
  __shared__ unsigned long long red[256];
  for (int i = tid; i < NN; i += 256) {
    unsigned u   = __float_as_uint(scores[b * NN + i]);
    unsigned ord = (u & 0x80000000u) ? ~u : (u | 0x80000000u);
    key[i] = ((unsigned long long)ord << 32) | (unsigned)(NN - 1 - i);
  }
  __syncthreads();
  for (int k = 0; k < NK; ++k) {
    unsigned long long m = 0;
    for (int i = tid; i < NN; i += 256) m = (key[i] > m) ? key[i] : m;
    red[tid] = m;
    __syncthreads();
    for (int s2 = 128; s2 > 0; s2 >>= 1) {
      if (tid < s2) { if (red[tid + s2] > red[tid]) red[tid] = red[tid + s2]; }
      __syncthreads();
    }
    if (tid == 0) {
      int n = (NN - 1) - (int)(red[0] & 0xFFFFFFFFull);
      topidx[b * NK + k] = n;
      key[n] = 0;
    }
    __syncthreads();
  }
}

// ---------------------------------------------------------------------------
// K4a: projections for 400 selected spans. [UNCHANGED]
// ---------------------------------------------------------------------------
__global__ __launch_bounds__(256) void k4a_proj(const float* __restrict__ P,
                                                const int* __restrict__ starts,
                                                const int* __restrict__ lens,
                                                const int* __restrict__ topidx,
                                                const float* __restrict__ rel,
                                                const float* __restrict__ nota,
                                                float* __restrict__ proj) {
  const int gw   = blockIdx.x * 4 + (threadIdx.x >> 6);   // 0..399
  const int lane = threadIdx.x & 63;
  const int b = gw / NK, k = gw % NK;
  const int n  = topidx[b * NK + k];
  const int st = starts[b * NN + n];
  const int nt = lens[b * NN + n] + 1;
  const int en = st + nt;
  const float fnt = (float)nt;
  const float* ps = P + ((size_t)b * (NS + 1) + st) * NH + lane * 4;
  const float* pe = P + ((size_t)b * (NS + 1) + en) * NH + lane * 4;
  float4 e[3];
#pragma unroll
  for (int p = 0; p < 3; ++p) {
    float4 vs = *reinterpret_cast<const float4*>(ps + p * 256);
    float4 ve = *reinterpret_cast<const float4*>(pe + p * 256);
    e[p].x = (ve.x - vs.x) / fnt;
    e[p].y = (ve.y - vs.y) / fnt;
    e[p].z = (ve.z - vs.z) / fnt;
    e[p].w = (ve.w - vs.w) / fnt;
  }
  for (int w = 0; w < 48; ++w) {
    const float* wr;
    if (w < 4)       wr = rel  + (size_t)w * (2 * NH);
    else if (w < 8)  wr = rel  + (size_t)(w - 4) * (2 * NH) + NH;
    else if (w < 28) wr = nota + (size_t)(w - 8) * (2 * NH);
    else             wr = nota + (size_t)(w - 28) * (2 * NH) + NH;
    wr += lane * 4;
    float d = 0.f;
#pragma unroll
    for (int p = 0; p < 3; ++p) {
      float4 wv = *reinterpret_cast<const float4*>(wr + p * 256);
      d += e[p].x * wv.x + e[p].y * wv.y + e[p].z * wv.z + e[p].w * wv.w;
    }
#pragma unroll
    for (int o = 32; o > 0; o >>= 1) d += __shfl_xor(d, o);
    if (lane == 0) proj[((size_t)b * NK + k) * 48 + w] = d;
  }
}

// ---------------------------------------------------------------------------
// K4b: epilogue. [UNCHANGED]
// ---------------------------------------------------------------------------
__global__ __launch_bounds__(256) void k4b_out(const float* __restrict__ proj,
                                               float* __restrict__ out) {
  int idx = blockIdx.x * 256 + threadIdx.x;
  if (idx >= NB * NK * NK) return;
  int b  = idx / (NK * NK);
  int rr = idx % (NK * NK);
  int k1 = rr / NK, k2 = rr % NK;
  const float* p1 = proj + ((size_t)b * NK + k1) * 48;
  const float* p2 = proj + ((size_t)b * NK + k2) * 48;
  float mx = p1[8] + p2[28];
#pragma unroll
  for (int m = 1; m < 20; ++m) mx = fmaxf(mx, p1[8 + m] + p2[28 + m]);
  float* o = out + (size_t)idx * 5;
  o[0] = mx;
#pragma unroll
  for (int r = 0; r < 4; ++r) o[1 + r] = p1[r] + p2[4 + r];
}

// ---------------------------------------------------------------------------
extern "C" void kernel_launch(void* const* d_in, const int* in_sizes, int n_in,
                              void* d_out, int out_size, void* d_ws, size_t ws_size,
                              hipStream_t stream) {
  const float* x      = (const float*)d_in[0];
  const int*   starts = (const int*)d_in[1];
  const int*   lens   = (const int*)d_in[2];
  const float* anchor = (const float*)d_in[3];
  const float* rel    = (const float*)d_in[4];
  const float* nota   = (const float*)d_in[5];
  float* out = (float*)d_out;

  char*  ws     = (char*)d_ws;
  size_t pbytes = (size_t)NB * (NS + 1) * NH * sizeof(float);  // ~100.7 MB
  float* P      = (float*)ws;
  float* scores = (float*)(ws + pbytes);
  int*   topidx = (int*)(ws + pbytes + (size_t)NB * NN * sizeof(float));
  float* proj   = (float*)(ws + pbytes + (size_t)NB * NN * sizeof(float) + 4096);
  float* chk    = (float*)(ws + pbytes + (size_t)NB * NN * sizeof(float) + 4096
                           + (size_t)NB * NK * 48 * sizeof(float));

  hipLaunchKernelGGL(k1a_chk, dim3(NB * (NH / 64)), dim3(256), 0, stream, x, chk);
  hipLaunchKernelGGL(k1b_fill, dim3(NB * (NH / 64) * NSEG / 4), dim3(256), 0, stream,
                     x, chk, P);
  hipLaunchKernelGGL(k2_scores, dim3(1024), dim3(256), 0, stream,
                     P, starts, lens, anchor, scores);
  hipLaunchKernelGGL(k3_topk, dim3(NB), dim3(256), 0, stream, scores, topidx);
  hipLaunchKernelGGL(k4a_proj, dim3(NB * NK / 4), dim3(256), 0, stream,
                     P, starts, lens, topidx, rel, nota, proj);
  hipLaunchKernelGGL(k4b_out, dim3((NB * NK * NK + 255) / 256), dim3(256), 0, stream,
                     proj, out);
}

// Round 7
// 103.028 us; speedup vs baseline: 2.5071x; 2.5071x over previous
//
#include <hip/hip_runtime.h>
#include <cstdint>
#include <cstddef>

#define NB 8
#define NS 4096
#define NN 2048
#define NH 768
#define NK 50

// ---------------------------------------------------------------------------
// KD: rowdot[b][c][s] = dot(x[b,s,:], anchor[c,:]).  One wave per 8
// consecutive rows; lane holds h = lane*4 + p*256 (3 float4 per row, fully
// coalesced 1KB wave-loads); 2-row software pipeline; shuffle-reduce; lane 0
// stores 3 f32. Memory-bound streaming of the full 100.7 MB input.
// ---------------------------------------------------------------------------
__global__ __launch_bounds__(256) void kd_rowdots(const float* __restrict__ x,
                                                  const float* __restrict__ anchor,
                                                  float* __restrict__ rowdot) {
  const int lane = threadIdx.x & 63;
  const int gw   = blockIdx.x * 4 + (threadIdx.x >> 6);   // 0..4095

  float4 a[3][3];
#pragma unroll
  for (int c = 0; c < 3; ++c)
#pragma unroll
    for (int p = 0; p < 3; ++p)
      a[c][p] = *reinterpret_cast<const float4*>(anchor + c * NH + p * 256 + lane * 4);

  const float* base = x + (size_t)gw * 8 * NH + lane * 4;

  float4 va[3], vb[3];
#pragma unroll
  for (int p = 0; p < 3; ++p)
    va[p] = *reinterpret_cast<const float4*>(base + p * 256);

#define KD_LOAD(V, I)                                                         \
  {                                                                           \
    const float* s_ = base + (size_t)(I) * NH;                                \
    _Pragma("unroll")                                                         \
    for (int p = 0; p < 3; ++p)                                               \
      V[p] = *reinterpret_cast<const float4*>(s_ + p * 256);                  \
  }
#define KD_CONS(V, I)                                                         \
  {                                                                           \
    float d0 = 0.f, d1 = 0.f, d2 = 0.f;                                       \
    _Pragma("unroll")                                                         \
    for (int p = 0; p < 3; ++p) {                                             \
      d0 += V[p].x * a[0][p].x + V[p].y * a[0][p].y +                         \
            V[p].z * a[0][p].z + V[p].w * a[0][p].w;                          \
      d1 += V[p].x * a[1][p].x + V[p].y * a[1][p].y +                         \
            V[p].z * a[1][p].z + V[p].w * a[1][p].w;                          \
      d2 += V[p].x * a[2][p].x + V[p].y * a[2][p].y +                         \
            V[p].z * a[2][p].z + V[p].w * a[2][p].w;                          \
    }                                                                         \
    _Pragma("unroll")                                                         \
    for (int o = 32; o > 0; o >>= 1) {                                        \
      d0 += __shfl_xor(d0, o);                                                \
      d1 += __shfl_xor(d1, o);                                                \
      d2 += __shfl_xor(d2, o);                                                \
    }                                                                         \
    if (lane == 0) {                                                          \
      int r = gw * 8 + (I);                                                   \
      int b = r >> 12, s = r & 4095;                                          \
      float* o_ = rowdot + (size_t)b * 3 * NS + s;                            \
      o_[0]      = d0;                                                        \
      o_[NS]     = d1;                                                        \
      o_[2 * NS] = d2;                                                        \
    }                                                                         \
  }

#pragma unroll
  for (int i = 0; i < 8; i += 2) {
    KD_LOAD(vb, i + 1)
    KD_CONS(va, i)
    if (i + 2 < 8) KD_LOAD(va, i + 2)
    KD_CONS(vb, i + 1)
  }
#undef KD_LOAD
#undef KD_CONS
}

// ---------------------------------------------------------------------------
// KS: span scores by linearity: score = max_c( sum_{r in span} rowdot[c][r] )
// / n_tok.  Thread per span; sorted starts -> neighboring threads read
// neighboring (L2-resident, 1.5 MB) table entries. Exact-duplicate spans
// produce bitwise-identical scores -> ties broken by index in K3.
// ---------------------------------------------------------------------------
__global__ __launch_bounds__(256) void ks_span(const float* __restrict__ rowdot,
                                               const int* __restrict__ starts,
                                               const int* __restrict__ lens,
                                               float* __restrict__ scores) {
  int sp = blockIdx.x * 256 + threadIdx.x;
  if (sp >= NB * NN) return;
  int b  = sp >> 11;
  int st = starts[sp];
  int n  = lens[sp] + 1;
  const float* rd = rowdot + (size_t)b * 3 * NS + st;
  float s0 = 0.f, s1 = 0.f, s2 = 0.f;
  for (int r = 0; r < n; ++r) {
    s0 += rd[r];
    s1 += rd[NS + r];
    s2 += rd[2 * NS + r];
  }
  scores[sp] = fmaxf(s0, fmaxf(s1, s2)) / (float)n;
}

// ---------------------------------------------------------------------------
// K3: top-50 per batch. Keys pack (orderable-f32 score, 2047-n) so max-key
// = (highest score, ties -> smallest index), matching lax.top_k. [UNCHANGED]
// ---------------------------------------------------------------------------
__global__ __launch_bounds__(256) void k3_topk(const float* __restrict__ scores,
                                               int* __restrict__ topidx) {
  const int b   = blockIdx.x;
  const int tid = threadIdx.x;
  __shared__ unsigned long long key[NN];
  __shared__ unsigned long long red[256];
  for (int i = tid; i < NN; i += 256) {
    unsigned u   = __float_as_uint(scores[b * NN + i]);
    unsigned ord = (u & 0x80000000u) ? ~u : (u | 0x80000000u);
    key[i] = ((unsigned long long)ord << 32) | (unsigned)(NN - 1 - i);
  }
  __syncthreads();
  for (int k = 0; k < NK; ++k) {
    unsigned long long m = 0;
    for (int i = tid; i < NN; i += 256) m = (key[i] > m) ? key[i] : m;
    red[tid] = m;
    __syncthreads();
    for (int s2 = 128; s2 > 0; s2 >>= 1) {
      if (tid < s2) { if (red[tid + s2] > red[tid]) red[tid] = red[tid + s2]; }
      __syncthreads();
    }
    if (tid == 0) {
      int n = (NN - 1) - (int)(red[0] & 0xFFFFFFFFull);
      topidx[b * NK + k] = n;
      key[n] = 0;
    }
    __syncthreads();
  }
}

// ---------------------------------------------------------------------------
// K4a: for the 400 selected spans: emb = (sum of span's x rows)/n_tok
// computed directly (<=8 coalesced row reads, L3-warm), then dot with the 48
// weight rows -> proj[b][k][48] = {rh[4], rt[4], nh[20], nt[20]}.
// ---------------------------------------------------------------------------
__global__ __launch_bounds__(256) void k4a_proj(const float* __restrict__ x,
                                                const int* __restrict__ starts,
                                                const int* __restrict__ lens,
                                                const int* __restrict__ topidx,
                                                const float* __restrict__ rel,
                                                const float* __restrict__ nota,
                                                float* __restrict__ proj) {
  const int gw   = blockIdx.x * 4 + (threadIdx.x >> 6);   // 0..399
  const int lane = threadIdx.x & 63;
  const int b = gw / NK, k = gw % NK;
  const int n  = topidx[b * NK + k];
  const int st = starts[b * NN + n];
  const int nt = lens[b * NN + n] + 1;
  const float fnt = (float)nt;

  float4 e[3];
#pragma unroll
  for (int p = 0; p < 3; ++p) { e[p].x = 0.f; e[p].y = 0.f; e[p].z = 0.f; e[p].w = 0.f; }
  for (int r = 0; r < nt; ++r) {
    const float* row = x + ((size_t)b * NS + st + r) * NH + lane * 4;
#pragma unroll
    for (int p = 0; p < 3; ++p) {
      float4 v = *reinterpret_cast<const float4*>(row + p * 256);
      e[p].x += v.x; e[p].y += v.y; e[p].z += v.z; e[p].w += v.w;
    }
  }
#pragma unroll
  for (int p = 0; p < 3; ++p) {
    e[p].x /= fnt; e[p].y /= fnt; e[p].z /= fnt; e[p].w /= fnt;
  }

  for (int w = 0; w < 48; ++w) {
    const float* wr;
    if (w < 4)       wr = rel  + (size_t)w * (2 * NH);
    else if (w < 8)  wr = rel  + (size_t)(w - 4) * (2 * NH) + NH;
    else if (w < 28) wr = nota + (size_t)(w - 8) * (2 * NH);
    else             wr = nota + (size_t)(w - 28) * (2 * NH) + NH;
    wr += lane * 4;
    float d = 0.f;
#pragma unroll
    for (int p = 0; p < 3; ++p) {
      float4 wv = *reinterpret_cast<const float4*>(wr + p * 256);
      d += e[p].x * wv.x + e[p].y * wv.y + e[p].z * wv.z + e[p].w * wv.w;
    }
#pragma unroll
    for (int o = 32; o > 0; o >>= 1) d += __shfl_xor(d, o);
    if (lane == 0) proj[((size_t)b * NK + k) * 48 + w] = d;
  }
}

// ---------------------------------------------------------------------------
// K4b: out[b,k1,k2,0] = max_m(nh[k1,m]+nt[k2,m]); out[b,k1,k2,1+r] = rh+rt.
// [UNCHANGED]
// ---------------------------------------------------------------------------
__global__ __launch_bounds__(256) void k4b_out(const float* __restrict__ proj,
                                               float* __restrict__ out) {
  int idx = blockIdx.x * 256 + threadIdx.x;
  if (idx >= NB * NK * NK) return;
  int b  = idx / (NK * NK);
  int rr = idx % (NK * NK);
  int k1 = rr / NK, k2 = rr % NK;
  const float* p1 = proj + ((size_t)b * NK + k1) * 48;
  const float* p2 = proj + ((size_t)b * NK + k2) * 48;
  float mx = p1[8] + p2[28];
#pragma unroll
  for (int m = 1; m < 20; ++m) mx = fmaxf(mx, p1[8 + m] + p2[28 + m]);
  float* o = out + (size_t)idx * 5;
  o[0] = mx;
#pragma unroll
  for (int r = 0; r < 4; ++r) o[1 + r] = p1[r] + p2[4 + r];
}

// ---------------------------------------------------------------------------
extern "C" void kernel_launch(void* const* d_in, const int* in_sizes, int n_in,
                              void* d_out, int out_size, void* d_ws, size_t ws_size,
                              hipStream_t stream) {
  const float* x      = (const float*)d_in[0];
  const int*   starts = (const int*)d_in[1];
  const int*   lens   = (const int*)d_in[2];
  const float* anchor = (const float*)d_in[3];
  const float* rel    = (const float*)d_in[4];
  const float* nota   = (const float*)d_in[5];
  float* out = (float*)d_out;

  char* ws = (char*)d_ws;
  float* rowdot = (float*)ws;                                    // 1.5 MB
  float* scores = (float*)(ws + (size_t)NB * 3 * NS * sizeof(float));
  int*   topidx = (int*)(ws + (size_t)NB * 3 * NS * sizeof(float)
                            + (size_t)NB * NN * sizeof(float));
  float* proj   = (float*)(ws + (size_t)NB * 3 * NS * sizeof(float)
                              + (size_t)NB * NN * sizeof(float) + 4096);

  hipLaunchKernelGGL(kd_rowdots, dim3(1024), dim3(256), 0, stream, x, anchor, rowdot);
  hipLaunchKernelGGL(ks_span, dim3(NB * NN / 256), dim3(256), 0, stream,
                     rowdot, starts, lens, scores);
  hipLaunchKernelGGL(k3_topk, dim3(NB), dim3(256), 0, stream, scores, topidx);
  hipLaunchKernelGGL(k4a_proj, dim3(NB * NK / 4), dim3(256), 0, stream,
                     x, starts, lens, topidx, rel, nota, proj);
  hipLaunchKernelGGL(k4b_out, dim3((NB * NK * NK + 255) / 256), dim3(256), 0, stream,
                     proj, out);
}